// Round 15
// baseline (221.625 us; speedup 1.0000x reference)
//
#include <hip/hip_runtime.h>
#include <hip/hip_bf16.h>
#include <math.h>

#define NTOK  32768
#define GNEPS 1e-5f

typedef __attribute__((ext_vector_type(4))) float f32x4;
typedef __attribute__((ext_vector_type(8))) short s16x8;
typedef __attribute__((ext_vector_type(4))) unsigned short u16x4;
typedef __attribute__((ext_vector_type(4))) unsigned int u32x4;

__device__ __forceinline__ unsigned short f2b(float f) {
  unsigned int u = __float_as_uint(f);
  unsigned int r = (u + 0x7FFFu + ((u >> 16) & 1u)) >> 16;
  return (unsigned short)r;
}
__device__ __forceinline__ float b2f(unsigned short s) {
  return __uint_as_float(((unsigned int)s) << 16);
}
// float -> OCP e4m3fn (saturating)
__device__ __forceinline__ unsigned char f2f8(float f) {
#if __has_builtin(__builtin_amdgcn_cvt_pk_fp8_f32)
  return (unsigned char)(__builtin_amdgcn_cvt_pk_fp8_f32(f, f, 0, false) & 0xff);
#else
  unsigned int u = __float_as_uint(f);
  unsigned int sgn = (u >> 24) & 0x80;
  float af = fabsf(f);
  if (af > 448.f) return (unsigned char)(sgn | 0x7E);
  if (af < 1e-10f) return (unsigned char)sgn;
  int e; float m = frexpf(af, &e);
  int ee = e + 6;
  if (ee < 1) { m = ldexpf(m, ee - 1); ee = 0; m *= 2.f; }
  int mant = (int)(m * 16.f + 0.5f) - 8;
  if (mant >= 8) { mant = 0; ee += 1; }
  if (mant < 0) mant = 0;
  if (ee > 15) return (unsigned char)(sgn | 0x7E);
  return (unsigned char)(sgn | (ee << 3) | mant);
#endif
}
// pack 4 floats -> 4 fp8 bytes in a u32
__device__ __forceinline__ unsigned int pk4f8(float a, float b, float c, float d) {
#if __has_builtin(__builtin_amdgcn_cvt_pk_fp8_f32)
  unsigned int p = (unsigned int)__builtin_amdgcn_cvt_pk_fp8_f32(a, b, 0, false);
  return (unsigned int)__builtin_amdgcn_cvt_pk_fp8_f32(c, d, (int)p, true);
#else
  return (unsigned int)f2f8(a) | ((unsigned int)f2f8(b) << 8)
       | ((unsigned int)f2f8(c) << 16) | ((unsigned int)f2f8(d) << 24);
#endif
}

__device__ __forceinline__ void stage16(const unsigned short* g, unsigned short* ldsChunkBase, int lane) {
#if __has_builtin(__builtin_amdgcn_global_load_lds)
  __builtin_amdgcn_global_load_lds((const __attribute__((address_space(1))) void*)g,
                                   (__attribute__((address_space(3))) void*)ldsChunkBase, 16, 0, 0);
#else
  *(s16x8*)((char*)ldsChunkBase + lane * 16) = *(const s16x8*)g;
#endif
}
__device__ __forceinline__ void stage16b(const unsigned char* g, unsigned char* ldsChunkBase, int lane) {
#if __has_builtin(__builtin_amdgcn_global_load_lds)
  __builtin_amdgcn_global_load_lds((const __attribute__((address_space(1))) void*)g,
                                   (__attribute__((address_space(3))) void*)ldsChunkBase, 16, 0, 0);
#else
  *(f32x4*)(ldsChunkBase + lane * 16) = *(const f32x4*)g;
#endif
}

// ---- workspace layout (bytes) ----
#define OFF_GSTAT   0u                // 32 f32
#define OFF_SSUM    4224u             // 1024 f32
#define OFF_CTX     8320u             // 131072 (unnormalized, scaled 1/16)
#define OFF_WCTX8   139392u           // 4*256*256 fp8 = 262144
#define OFF_BIASP   401536u           // 4*768 f32 = 12288
#define OFF_WP      413824u           // 768*256*4 bf16 = 1572864
#define OFF_XT      1986688u          // 4*32768*256 bf16 = 67108864
#define OFF_QT      69095552u         // 4*32768*256 fp8 = 33554432 (SOFTMAXED q)
#define OFF_KVB     102649984u        // 4*512*32768 fp8 = 67108864
#define WS_NEEDED   (OFF_KVB + 67108864ull)

// ------------------------------------------------------------------
// K1: fused GN stats + raw-x bf16 cast + transpose -> xT [b][n][c]
// ------------------------------------------------------------------
__global__ __launch_bounds__(256) void gn_fused(const float* __restrict__ x,
                                                float* __restrict__ gstat,
                                                unsigned short* __restrict__ xT) {
  __shared__ unsigned short s1[256 * 64];
  __shared__ float rs[4][4], rq[4][4];
  int b = blockIdx.y;
  int n0 = blockIdx.x * 64;
  int tid = threadIdx.x;
  const float* xb = x + (size_t)b * 256 * NTOK;
  float s[4] = {0.f, 0.f, 0.f, 0.f}, sq[4] = {0.f, 0.f, 0.f, 0.f};
#pragma unroll
  for (int it = 0; it < 16; ++it) {
    int idx = tid + it * 256;
    int c = idx >> 4, q = idx & 15;
    f32x4 v = *reinterpret_cast<const f32x4*>(&xb[(size_t)c * NTOK + n0 + q * 4]);
    const int g = it >> 2;
    s[g]  += v.x + v.y + v.z + v.w;
    sq[g] += v.x * v.x + v.y * v.y + v.z * v.z + v.w * v.w;
    u16x4 o = { f2b(v.x), f2b(v.y), f2b(v.z), f2b(v.w) };
    int phys = (q * 4 + (c >> 3) * 4) & 63;
    *reinterpret_cast<u16x4*>(&s1[c * 64 + phys]) = o;
  }
  int lane = tid & 63, w = tid >> 6;
#pragma unroll
  for (int g = 0; g < 4; ++g) {
    float a = s[g], bq = sq[g];
    for (int o = 32; o > 0; o >>= 1) { a += __shfl_down(a, o); bq += __shfl_down(bq, o); }
    if (lane == 0) { rs[w][g] = a; rq[w][g] = bq; }
  }
  __syncthreads();
  if (tid < 8) {
    int g = tid >> 1, part = tid & 1;
    float v = part ? (rq[0][g] + rq[1][g] + rq[2][g] + rq[3][g])
                   : (rs[0][g] + rs[1][g] + rs[2][g] + rs[3][g]);
    atomicAdd(&gstat[2 * (b * 4 + g) + part], v);
  }
#pragma unroll
  for (int it = 0; it < 8; ++it) {
    int task = tid + it * 256;
    int n = task >> 5, oc = task & 31;
    int phys = (n + oc * 4) & 63;
    s16x8 pk;
#pragma unroll
    for (int i = 0; i < 8; ++i) pk[i] = (short)s1[(oc * 8 + i) * 64 + phys];
    *reinterpret_cast<s16x8*>(&xT[((size_t)(b * NTOK + n0 + n)) * 256 + oc * 8]) = pk;
  }
}

// ------------------------------------------------------------------
// K2: finalize stats + fold GN into weights
// ------------------------------------------------------------------
__global__ __launch_bounds__(256) void fold_w(const float* __restrict__ wqkv,
                                              const float* __restrict__ gamma,
                                              const float* __restrict__ beta,
                                              const float* __restrict__ gstat,
                                              unsigned short* __restrict__ Wp,
                                              float* __restrict__ biasp) {
  int o = blockIdx.x, b = blockIdx.y;
  int c = threadIdx.x;
  int g = c >> 6;
  const float cnt = 64.f * (float)NTOK;
  float mu  = gstat[2 * (b * 4 + g)] / cnt;
  float var = gstat[2 * (b * 4 + g) + 1] / cnt - mu * mu;
  float rsig = rsqrtf(var + GNEPS);
  float wv = wqkv[(size_t)o * 256 + c];
  float A = gamma[c] * rsig;
  float Bc = beta[c] - mu * A;
  Wp[((size_t)b * 768 + o) * 256 + c] = f2b(wv * A);
  float t = wv * Bc;
  int lane = c & 63, w = c >> 6;
  for (int off = 32; off > 0; off >>= 1) t += __shfl_down(t, off);
  __shared__ float red[4];
  if (lane == 0) red[w] = t;
  __syncthreads();
  if (c == 0) biasp[b * 768 + o] = red[0] + red[1] + red[2] + red[3];
}

// ------------------------------------------------------------------
// K3: qkv GEMM, 256x128 tile, 512 thr, m97 2-barrier loop (bf16).
// Epilogue: bias; q -> softmax -> qT FP8 [n][c]; k -> exp/16 fp8,
// v -> fp8, into kvb with context-tile swizzle baked in.
// ------------------------------------------------------------------
__global__ __launch_bounds__(512, 4) void qkv_gemm(const unsigned short* __restrict__ Wp,
                                                   const float* __restrict__ biasp,
                                                   const unsigned short* __restrict__ xT,
                                                   unsigned char* __restrict__ qT8,
                                                   unsigned char* __restrict__ kvb8) {
  __shared__ unsigned short smem[24576];
  unsigned short* As = smem;
  unsigned short* Bs = smem + 16384;
  int bid = blockIdx.x;
  int L = (bid & 7) * 384 + (bid >> 3);
  int ot = L % 3;
  int t2 = L / 3;
  int b = t2 & 3, nt = t2 >> 2;
  int n0 = nt * 128;
  int tid = threadIdx.x;
  int w = tid >> 6, l = tid & 63;
  int hi = (l >> 4) & 3, lo = l & 15;
  int wo = w >> 1, wn = w & 1;
  int lr = l >> 3, lj = l & 7;
  int srcj = lj ^ lr;
  const unsigned short* Abase = Wp + ((size_t)(b * 768 + ot * 256)) * 256;
  const unsigned short* Bbase = xT + ((size_t)(b * NTOK + n0)) * 256;

  f32x4 acc[4][4];
#pragma unroll
  for (int s = 0; s < 4; ++s)
#pragma unroll
    for (int n = 0; n < 4; ++n) acc[s][n] = (f32x4){0.f, 0.f, 0.f, 0.f};

  for (int c0 = 0; c0 < 256; c0 += 64) {
    __syncthreads();
#pragma unroll
    for (int q = 0; q < 4; ++q) {
      int chunk = w * 4 + q; int row = chunk * 8 + lr;
      stage16(Abase + (size_t)row * 256 + c0 + srcj * 8, As + chunk * 512, l);
    }
#pragma unroll
    for (int q = 0; q < 2; ++q) {
      int chunk = w * 2 + q; int row = chunk * 8 + lr;
      stage16(Bbase + (size_t)row * 256 + c0 + srcj * 8, Bs + chunk * 512, l);
    }
    __syncthreads();
#pragma unroll
    for (int t = 0; t < 2; ++t) {
      s16x8 af[4], bf[4];
#pragma unroll
      for (int s = 0; s < 4; ++s) {
        int row = wo * 64 + s * 16 + lo;
        int phys = (t * 4 + hi) ^ (row & 7);
        af[s] = *reinterpret_cast<const s16x8*>(&As[row * 64 + phys * 8]);
      }
#pragma unroll
      for (int n = 0; n < 4; ++n) {
        int row = wn * 64 + n * 16 + lo;
        int phys = (t * 4 + hi) ^ (row & 7);
        bf[n] = *reinterpret_cast<const s16x8*>(&Bs[row * 64 + phys * 8]);
      }
#pragma unroll
      for (int s = 0; s < 4; ++s)
#pragma unroll
        for (int n = 0; n < 4; ++n)
          acc[s][n] = __builtin_amdgcn_mfma_f32_16x16x32_bf16(af[s], bf[n], acc[s][n], 0, 0, 0);
    }
  }

  // bias add
#pragma unroll
  for (int s = 0; s < 4; ++s)
#pragma unroll
    for (int i = 0; i < 4; ++i) {
      float bv = biasp[b * 768 + ot * 256 + wo * 64 + s * 16 + hi * 4 + i];
#pragma unroll
      for (int n = 0; n < 4; ++n) acc[s][n][i] += bv;
    }

  if (ot == 0) {
    // q: transpose -> bounce [64n][264] bf16, softmax per (n,head), fp8 store
    for (int r = 0; r < 2; ++r) {
      __syncthreads();
      if (wn == r) {
#pragma unroll
        for (int s = 0; s < 4; ++s)
#pragma unroll
          for (int n = 0; n < 4; ++n)
#pragma unroll
            for (int i = 0; i < 4; ++i) {
              int o_l = wo * 64 + s * 16 + hi * 4 + i;
              int n_l = n * 16 + lo;
              smem[n_l * 264 + o_l] = f2b(acc[s][n][i]);
            }
      }
      __syncthreads();
      {
        int n_l = tid >> 3, h = tid & 7;
        unsigned short* rowp = &smem[n_l * 264 + h * 32];
        float v[32];
        float m = -1e30f;
#pragma unroll
        for (int i = 0; i < 32; ++i) { v[i] = b2f(rowp[i]); m = fmaxf(m, v[i]); }
        float ssum = 0.f;
#pragma unroll
        for (int i = 0; i < 32; ++i) { v[i] = __expf(v[i] - m); ssum += v[i]; }
        float rr = 1.f / ssum;
#pragma unroll
        for (int i = 0; i < 32; ++i) rowp[i] = f2b(v[i] * rr);
      }
      __syncthreads();
#pragma unroll
      for (int it = 0; it < 2; ++it) {
        int task = tid + it * 512;                 // 1024 = 64n x 16 slots (16B fp8)
        int n_l = task >> 4, j = task & 15;
        const unsigned short* src = &smem[n_l * 264 + j * 16];
        u32x4 pk;
#pragma unroll
        for (int q2 = 0; q2 < 4; ++q2)
          pk[q2] = pk4f8(b2f(src[q2 * 4]), b2f(src[q2 * 4 + 1]),
                         b2f(src[q2 * 4 + 2]), b2f(src[q2 * 4 + 3]));
        *reinterpret_cast<u32x4*>(&qT8[((size_t)(b * NTOK + n0 + r * 64 + n_l)) * 256 + j * 16]) = pk;
      }
    }
  } else {
    // k/v -> fp8 bounce [128o][144], 16B stores with baked-in swizzle
    unsigned char* smem8 = reinterpret_cast<unsigned char*>(smem);
    int vbase = (ot == 1) ? 0 : 256;
    for (int r = 0; r < 2; ++r) {
      __syncthreads();
      if ((wo >> 1) == r) {
#pragma unroll
        for (int s = 0; s < 4; ++s)
#pragma unroll
          for (int n = 0; n < 4; ++n)
#pragma unroll
            for (int i = 0; i < 4; ++i) {
              int o_l = (wo & 1) * 64 + s * 16 + hi * 4 + i;
              int n_l = wn * 64 + n * 16 + lo;
              float val = acc[s][n][i];
              smem8[o_l * 144 + n_l] = (ot == 1) ? f2f8(__expf(val) * 0.0625f)
                                                 : f2f8(val);
            }
      }
      __syncthreads();
#pragma unroll
      for (int it = 0; it < 2; ++it) {
        int task = tid + it * 512;
        int o_l = task >> 3, j = task & 7;
        f32x4 v = *reinterpret_cast<const f32x4*>(&smem8[o_l * 144 + j * 16]);
        int row = vbase + r * 128 + o_l;
        int local16 = ((n0 & 511) >> 4) + j;
        int phys16 = local16 ^ (row & 7);
        *reinterpret_cast<f32x4*>(&kvb8[((size_t)(b * 512 + row)) * 32768
                                        + (n0 & ~511) + phys16 * 16]) = v;
      }
    }
  }
}

// ------------------------------------------------------------------
// K4: context via FP8 MFMA (E=exp(k)/16, V=v; scale cancels in ratio).
// ------------------------------------------------------------------
__global__ __launch_bounds__(256) void context_mfma(const unsigned char* __restrict__ kvb8,
                                                    float* __restrict__ ctx,
                                                    float* __restrict__ Ssum) {
  __shared__ unsigned char ctile[32768];
  unsigned char* kl = ctile;
  unsigned char* vl = ctile + 16384;
  int bh = blockIdx.y;
  int b = bh >> 3, h = bh & 7;
  int n0 = blockIdx.x * 512;
  int tid = threadIdx.x;
  int w = tid >> 6, l = tid & 63;
  int lo = l & 15, hi = l >> 4;
  const unsigned char* kb = kvb8 + ((size_t)(b * 512 + h * 32)) * 32768 + n0;
  const unsigned char* vb = kvb8 + ((size_t)(b * 512 + 256 + h * 32)) * 32768 + n0;

#pragma unroll
  for (int q = 0; q < 4; ++q) {
    int chunk = w * 4 + q;
    int row = chunk * 2 + (l >> 5);
    int blk = l & 31;
    stage16b(kb + (size_t)row * 32768 + blk * 16, kl + chunk * 1024, l);
    stage16b(vb + (size_t)row * 32768 + blk * 16, vl + chunk * 1024, l);
  }
  __syncthreads();

  f32x4 acc[2][2], accS[2];
#pragma unroll
  for (int fr = 0; fr < 2; ++fr) {
    accS[fr] = (f32x4){0.f, 0.f, 0.f, 0.f};
#pragma unroll
    for (int fc = 0; fc < 2; ++fc) acc[fr][fc] = (f32x4){0.f, 0.f, 0.f, 0.f};
  }
  long ones = 0x3838383838383838L;

#pragma unroll
  for (int ks = 0; ks < 4; ++ks) {
    int tb = w * 16 + ks * 4 + hi;
    long af[2], bf[2];
#pragma unroll
    for (int fr = 0; fr < 2; ++fr) {
      int row = fr * 16 + lo;
      int off = row * 512 + (((tb >> 1) ^ (row & 7)) << 4) + ((tb & 1) << 3);
      af[fr] = *reinterpret_cast<const long*>(&kl[off]);
      bf[fr] = *reinterpret_cast<const long*>(&vl[off]);
    }
#pragma unroll
    for (int fr = 0; fr < 2; ++fr) {
#pragma unroll
      for (int fc = 0; fc < 2; ++fc)
        acc[fr][fc] = __builtin_amdgcn_mfma_f32_16x16x32_fp8_fp8(af[fr], bf[fc], acc[fr][fc], 0, 0, 0);
      accS[fr] = __builtin_amdgcn_mfma_f32_16x16x32_fp8_fp8(af[fr], ones, accS[fr], 0, 0, 0);
    }
  }
  __syncthreads();

  float* lpart = reinterpret_cast<float*>(ctile);
  float* mine = lpart + w * 1056;
#pragma unroll
  for (int fr = 0; fr < 2; ++fr) {
#pragma unroll
    for (int fc = 0; fc < 2; ++fc)
#pragma unroll
      for (int i = 0; i < 4; ++i) {
        int row = fr * 16 + hi * 4 + i;
        int col = fc * 16 + lo;
        mine[row * 32 + col] = acc[fr][fc][i];
      }
    if (lo == 0)
#pragma unroll
      for (int i = 0; i < 4; ++i)
        mine[1024 + fr * 16 + hi * 4 + i] = accS[fr][i];
  }
  __syncthreads();
  float* cb = ctx + (size_t)bh * 1024;
  for (int i = tid; i < 1024; i += 256) {
    float v = lpart[i] + lpart[1056 + i] + lpart[2112 + i] + lpart[3168 + i];
    atomicAdd(&cb[i], v);
  }
  if (tid < 32) {
    int i = 1024 + tid;
    float v = lpart[i] + lpart[1056 + i] + lpart[2112 + i] + lpart[3168 + i];
    atomicAdd(&Ssum[b * 256 + h * 32 + tid], v);
  }
}

// ------------------------------------------------------------------
// K5: wctx8 = fp8( (1/Ssum) * wout @ ctx~ )
// ------------------------------------------------------------------
__global__ __launch_bounds__(256) void make_wctx(const float* __restrict__ wout,
                                                 const float* __restrict__ ctx,
                                                 const float* __restrict__ Ssum,
                                                 unsigned char* __restrict__ wctx8) {
  int o = blockIdx.x, b = blockIdx.y;
  int tid = threadIdx.x;
  int h = tid >> 5, d = tid & 31;
  const float* cb = ctx + ((size_t)(b * 8 + h)) * 1024 + d * 32;
  const float* wr = wout + (size_t)o * 256 + h * 32;
  float s = 0.f;
#pragma unroll
  for (int e = 0; e < 32; ++e) s += wr[e] * cb[e];
  s *= (1.f / Ssum[b * 256 + tid]);
  wctx8[((size_t)b * 256 + o) * 256 + tid] = f2f8(s);
}

// ------------------------------------------------------------------
// K6: out = wctx8 @ q8 + bias + x.  FP8xFP8 MFMA, BK=128 per outer step
// (2 outer steps, half the barriers), 48KB LDS, conflict-free 128B rows.
// f32x4 epilogue via bounce.
// ------------------------------------------------------------------
__global__ __launch_bounds__(512, 4) void out_gemm(const unsigned char* __restrict__ wctx8,
                                                   const unsigned char* __restrict__ qT8,
                                                   const float* __restrict__ bout,
                                                   const float* __restrict__ x,
                                                   float* __restrict__ out) {
  __shared__ unsigned char smem8[49152];   // As [0,32768) 256x128B, Bs [32768,49152) 128x128B
  unsigned char* As = smem8;
  unsigned char* Bs = smem8 + 32768;
  int bid = blockIdx.x;
  int L = (bid & 7) * 128 + (bid >> 3);    // 1024 = 8*128
  int b = L >> 8, nt = L & 255;
  int n0 = nt * 128;
  int tid = threadIdx.x;
  int w = tid >> 6, l = tid & 63;
  int hi = (l >> 4) & 3, lo = l & 15;
  int wo = w >> 1, wn = w & 1;
  int lr = l >> 3, lj = l & 7;             // staging: 8 rows/chunk, 8 lanes x 16B per row
  int srcj = lj ^ lr;
  const unsigned char* Abase = wctx8 + (size_t)b * 65536;
  const unsigned char* Bbase = qT8 + ((size_t)(b * NTOK + n0)) * 256;

  f32x4 acc[4][4];
#pragma unroll
  for (int s = 0; s < 4; ++s)
#pragma unroll
    for (int n = 0; n < 4; ++n) acc[s][n] = (f32x4){0.f, 0.f, 0.f, 0.f};

  for (int c0 = 0; c0 < 256; c0 += 128) {
    __syncthreads();
#pragma unroll
    for (int q = 0; q < 4; ++q) {          // A: 32 chunks of 1KB (8 rows x 128B)
      int chunk = w * 4 + q; int row = chunk * 8 + lr;
      stage16b(Abase + (size_t)row * 256 + c0 + srcj * 16, As + chunk * 1024, l);
    }
#pragma unroll
    for (int q = 0; q < 2; ++q) {          // B: 16 chunks
      int chunk = w * 2 + q; int row = chunk * 8 + lr;
      stage16b(Bbase + (size_t)row * 256 + c0 + srcj * 16, Bs + chunk * 1024, l);
    }
    __syncthreads();
#pragma unroll
    for (int t = 0; t < 4; ++t) {          // K=32 per t
      int blk16 = t * 2 + (hi >> 1);
      int sub8  = (hi & 1) * 8;
      long af[4], bf[4];
#pragma unroll
      for (int s = 0; s < 4; ++s) {
        int row = wo * 64 + s * 16 + lo;
        af[s] = *reinterpret_cast<const long*>(&As[row * 128 + ((blk16 ^ (row & 7)) << 4) + sub8]);
      }
#pragma unroll
      for (int n = 0; n < 4; ++n) {
        int row = wn * 64 + n * 16 + lo;
        bf[n] = *reinterpret_cast<const long*>(&Bs[row * 128 + ((blk16 ^ (row & 7)) << 4) + sub8]);
      }
#pragma unroll
      for (int s = 0; s < 4; ++s)
#pragma unroll
        for (int n = 0; n < 4; ++n)
          acc[s][n] = __builtin_amdgcn_mfma_f32_16x16x32_fp8_fp8(af[s], bf[n], acc[s][n], 0, 0, 0);
    }
  }

  // epilogue: f32 bounce [64][132], coalesced f32x4 RMW out = acc + bias + x
  float* bounce = reinterpret_cast<float*>(smem8);
  const float* xb = x + (size_t)b * 256 * NTOK;
  for (int r = 0; r < 4; ++r) {
    __syncthreads();
    if (wo == r) {
#pragma unroll
      for (int s = 0; s < 4; ++s)
#pragma unroll
        for (int n = 0; n < 4; ++n)
#pragma unroll
          for (int i = 0; i < 4; ++i) {
            int o_l = s * 16 + hi * 4 + i;
            int n_l = wn * 64 + n * 16 + lo;
            bounce[o_l * 132 + n_l] = acc[s][n][i];
          }
    }
    __syncthreads();
#pragma unroll
    for (int it = 0; it < 4; ++it) {
      int task = tid + it * 512;
      int o_l = task >> 5, q4 = task & 31;
      int o = r * 64 + o_l;
      f32x4 a = *reinterpret_cast<const f32x4*>(&bounce[o_l * 132 + q4 * 4]);
      f32x4 xv = *reinterpret_cast<const f32x4*>(&xb[(size_t)o * NTOK + n0 + q4 * 4]);
      float bo = bout[o];
      f32x4 rlt = { a.x + bo + xv.x, a.y + bo + xv.y, a.z + bo + xv.z, a.w + bo + xv.w };
      *reinterpret_cast<f32x4*>(&out[((size_t)b * 256 + o) * NTOK + n0 + q4 * 4]) = rlt;
    }
  }
}

// ------------------------------------------------------------------
extern "C" void kernel_launch(void* const* d_in, const int* in_sizes, int n_in,
                              void* d_out, int out_size, void* d_ws, size_t ws_size,
                              hipStream_t stream) {
  const float* x     = (const float*)d_in[0];
  const float* gamma = (const float*)d_in[1];
  const float* beta  = (const float*)d_in[2];
  const float* wqkv  = (const float*)d_in[3];
  const float* wout  = (const float*)d_in[4];
  const float* bout  = (const float*)d_in[5];
  float* out = (float*)d_out;

  if (ws_size < WS_NEEDED) return;

  char* ws = (char*)d_ws;
  float* gstat        = (float*)(ws + OFF_GSTAT);
  float* Ssum         = (float*)(ws + OFF_SSUM);
  float* ctx          = (float*)(ws + OFF_CTX);
  unsigned char* wctx8 = (unsigned char*)(ws + OFF_WCTX8);
  float* biasp        = (float*)(ws + OFF_BIASP);
  unsigned short* Wp  = (unsigned short*)(ws + OFF_WP);
  unsigned short* xT  = (unsigned short*)(ws + OFF_XT);
  unsigned char* qT8  = (unsigned char*)(ws + OFF_QT);
  unsigned char* kvb8 = (unsigned char*)(ws + OFF_KVB);

  // zero: gstat, Ssum, ctx
  hipMemsetAsync(ws, 0, OFF_CTX + 131072u, stream);

  gn_fused  <<<dim3(512, 4), 256, 0, stream>>>(x, gstat, xT);
  fold_w    <<<dim3(768, 4), 256, 0, stream>>>(wqkv, gamma, beta, gstat, Wp, biasp);
  qkv_gemm  <<<3072, 512, 0, stream>>>(Wp, biasp, xT, qT8, kvb8);
  context_mfma<<<dim3(64, 32), 256, 0, stream>>>(kvb8, ctx, Ssum);
  make_wctx <<<dim3(256, 4), 256, 0, stream>>>(wout, ctx, Ssum, wctx8);
  out_gemm  <<<1024, 512, 0, stream>>>(wctx8, qT8, bout, x, out);
}

// Round 16
// 220.210 us; speedup vs baseline: 1.0064x; 1.0064x over previous
//
#include <hip/hip_runtime.h>
#include <hip/hip_bf16.h>
#include <math.h>

#define NTOK  32768
#define GNEPS 1e-5f

typedef __attribute__((ext_vector_type(4))) float f32x4;
typedef __attribute__((ext_vector_type(8))) short s16x8;
typedef __attribute__((ext_vector_type(4))) unsigned short u16x4;
typedef __attribute__((ext_vector_type(4))) unsigned int u32x4;

__device__ __forceinline__ unsigned short f2b(float f) {
  unsigned int u = __float_as_uint(f);
  unsigned int r = (u + 0x7FFFu + ((u >> 16) & 1u)) >> 16;
  return (unsigned short)r;
}
__device__ __forceinline__ float b2f(unsigned short s) {
  return __uint_as_float(((unsigned int)s) << 16);
}
// float -> OCP e4m3fn (saturating)
__device__ __forceinline__ unsigned char f2f8(float f) {
#if __has_builtin(__builtin_amdgcn_cvt_pk_fp8_f32)
  return (unsigned char)(__builtin_amdgcn_cvt_pk_fp8_f32(f, f, 0, false) & 0xff);
#else
  unsigned int u = __float_as_uint(f);
  unsigned int sgn = (u >> 24) & 0x80;
  float af = fabsf(f);
  if (af > 448.f) return (unsigned char)(sgn | 0x7E);
  if (af < 1e-10f) return (unsigned char)sgn;
  int e; float m = frexpf(af, &e);
  int ee = e + 6;
  if (ee < 1) { m = ldexpf(m, ee - 1); ee = 0; m *= 2.f; }
  int mant = (int)(m * 16.f + 0.5f) - 8;
  if (mant >= 8) { mant = 0; ee += 1; }
  if (mant < 0) mant = 0;
  if (ee > 15) return (unsigned char)(sgn | 0x7E);
  return (unsigned char)(sgn | (ee << 3) | mant);
#endif
}
// pack 4 floats -> 4 fp8 bytes in a u32
__device__ __forceinline__ unsigned int pk4f8(float a, float b, float c, float d) {
#if __has_builtin(__builtin_amdgcn_cvt_pk_fp8_f32)
  unsigned int p = (unsigned int)__builtin_amdgcn_cvt_pk_fp8_f32(a, b, 0, false);
  return (unsigned int)__builtin_amdgcn_cvt_pk_fp8_f32(c, d, (int)p, true);
#else
  return (unsigned int)f2f8(a) | ((unsigned int)f2f8(b) << 8)
       | ((unsigned int)f2f8(c) << 16) | ((unsigned int)f2f8(d) << 24);
#endif
}

__device__ __forceinline__ void stage16(const unsigned short* g, unsigned short* ldsChunkBase, int lane) {
#if __has_builtin(__builtin_amdgcn_global_load_lds)
  __builtin_amdgcn_global_load_lds((const __attribute__((address_space(1))) void*)g,
                                   (__attribute__((address_space(3))) void*)ldsChunkBase, 16, 0, 0);
#else
  *(s16x8*)((char*)ldsChunkBase + lane * 16) = *(const s16x8*)g;
#endif
}
__device__ __forceinline__ void stage16b(const unsigned char* g, unsigned char* ldsChunkBase, int lane) {
#if __has_builtin(__builtin_amdgcn_global_load_lds)
  __builtin_amdgcn_global_load_lds((const __attribute__((address_space(1))) void*)g,
                                   (__attribute__((address_space(3))) void*)ldsChunkBase, 16, 0, 0);
#else
  *(f32x4*)(ldsChunkBase + lane * 16) = *(const f32x4*)g;
#endif
}

// ---- workspace layout (bytes) ----
#define OFF_GSTAT   0u                // 32 f32
#define OFF_SSUM    4224u             // 1024 f32
#define OFF_CTX     8320u             // 131072 (unnormalized, scaled 1/16)
#define OFF_WCTX8   139392u           // 4*256*256 fp8 = 262144
#define OFF_BIASP   401536u           // 4*768 f32 = 12288
#define OFF_WP      413824u           // 768*256*4 bf16 = 1572864
#define OFF_XT      1986688u          // 4*32768*256 bf16 = 67108864
#define OFF_QT      69095552u         // 4*32768*256 fp8 = 33554432 (SOFTMAXED q)
#define OFF_KVB     102649984u        // 4*512*32768 fp8 = 67108864
#define WS_NEEDED   (OFF_KVB + 67108864ull)

// ------------------------------------------------------------------
// K1: fused GN stats + raw-x bf16 cast + transpose -> xT [b][n][c]
// ------------------------------------------------------------------
__global__ __launch_bounds__(256) void gn_fused(const float* __restrict__ x,
                                                float* __restrict__ gstat,
                                                unsigned short* __restrict__ xT) {
  __shared__ unsigned short s1[256 * 64];
  __shared__ float rs[4][4], rq[4][4];
  int b = blockIdx.y;
  int n0 = blockIdx.x * 64;
  int tid = threadIdx.x;
  const float* xb = x + (size_t)b * 256 * NTOK;
  float s[4] = {0.f, 0.f, 0.f, 0.f}, sq[4] = {0.f, 0.f, 0.f, 0.f};
#pragma unroll
  for (int it = 0; it < 16; ++it) {
    int idx = tid + it * 256;
    int c = idx >> 4, q = idx & 15;
    f32x4 v = *reinterpret_cast<const f32x4*>(&xb[(size_t)c * NTOK + n0 + q * 4]);
    const int g = it >> 2;
    s[g]  += v.x + v.y + v.z + v.w;
    sq[g] += v.x * v.x + v.y * v.y + v.z * v.z + v.w * v.w;
    u16x4 o = { f2b(v.x), f2b(v.y), f2b(v.z), f2b(v.w) };
    int phys = (q * 4 + (c >> 3) * 4) & 63;
    *reinterpret_cast<u16x4*>(&s1[c * 64 + phys]) = o;
  }
  int lane = tid & 63, w = tid >> 6;
#pragma unroll
  for (int g = 0; g < 4; ++g) {
    float a = s[g], bq = sq[g];
    for (int o = 32; o > 0; o >>= 1) { a += __shfl_down(a, o); bq += __shfl_down(bq, o); }
    if (lane == 0) { rs[w][g] = a; rq[w][g] = bq; }
  }
  __syncthreads();
  if (tid < 8) {
    int g = tid >> 1, part = tid & 1;
    float v = part ? (rq[0][g] + rq[1][g] + rq[2][g] + rq[3][g])
                   : (rs[0][g] + rs[1][g] + rs[2][g] + rs[3][g]);
    atomicAdd(&gstat[2 * (b * 4 + g) + part], v);
  }
#pragma unroll
  for (int it = 0; it < 8; ++it) {
    int task = tid + it * 256;
    int n = task >> 5, oc = task & 31;
    int phys = (n + oc * 4) & 63;
    s16x8 pk;
#pragma unroll
    for (int i = 0; i < 8; ++i) pk[i] = (short)s1[(oc * 8 + i) * 64 + phys];
    *reinterpret_cast<s16x8*>(&xT[((size_t)(b * NTOK + n0 + n)) * 256 + oc * 8]) = pk;
  }
}

// ------------------------------------------------------------------
// K2: finalize stats + fold GN into weights
// ------------------------------------------------------------------
__global__ __launch_bounds__(256) void fold_w(const float* __restrict__ wqkv,
                                              const float* __restrict__ gamma,
                                              const float* __restrict__ beta,
                                              const float* __restrict__ gstat,
                                              unsigned short* __restrict__ Wp,
                                              float* __restrict__ biasp) {
  int o = blockIdx.x, b = blockIdx.y;
  int c = threadIdx.x;
  int g = c >> 6;
  const float cnt = 64.f * (float)NTOK;
  float mu  = gstat[2 * (b * 4 + g)] / cnt;
  float var = gstat[2 * (b * 4 + g) + 1] / cnt - mu * mu;
  float rsig = rsqrtf(var + GNEPS);
  float wv = wqkv[(size_t)o * 256 + c];
  float A = gamma[c] * rsig;
  float Bc = beta[c] - mu * A;
  Wp[((size_t)b * 768 + o) * 256 + c] = f2b(wv * A);
  float t = wv * Bc;
  int lane = c & 63, w = c >> 6;
  for (int off = 32; off > 0; off >>= 1) t += __shfl_down(t, off);
  __shared__ float red[4];
  if (lane == 0) red[w] = t;
  __syncthreads();
  if (c == 0) biasp[b * 768 + o] = red[0] + red[1] + red[2] + red[3];
}

// ------------------------------------------------------------------
// K3: qkv GEMM, 256x128 tile, 512 thr, m97 2-barrier loop (bf16).
// Epilogue: bias; q -> softmax -> qT FP8 [n][c]; k -> exp/16 fp8,
// v -> fp8, into kvb with context-tile swizzle baked in.
// ------------------------------------------------------------------
__global__ __launch_bounds__(512, 4) void qkv_gemm(const unsigned short* __restrict__ Wp,
                                                   const float* __restrict__ biasp,
                                                   const unsigned short* __restrict__ xT,
                                                   unsigned char* __restrict__ qT8,
                                                   unsigned char* __restrict__ kvb8) {
  __shared__ unsigned short smem[24576];
  unsigned short* As = smem;
  unsigned short* Bs = smem + 16384;
  int bid = blockIdx.x;
  int L = (bid & 7) * 384 + (bid >> 3);
  int ot = L % 3;
  int t2 = L / 3;
  int b = t2 & 3, nt = t2 >> 2;
  int n0 = nt * 128;
  int tid = threadIdx.x;
  int w = tid >> 6, l = tid & 63;
  int hi = (l >> 4) & 3, lo = l & 15;
  int wo = w >> 1, wn = w & 1;
  int lr = l >> 3, lj = l & 7;
  int srcj = lj ^ lr;
  const unsigned short* Abase = Wp + ((size_t)(b * 768 + ot * 256)) * 256;
  const unsigned short* Bbase = xT + ((size_t)(b * NTOK + n0)) * 256;

  f32x4 acc[4][4];
#pragma unroll
  for (int s = 0; s < 4; ++s)
#pragma unroll
    for (int n = 0; n < 4; ++n) acc[s][n] = (f32x4){0.f, 0.f, 0.f, 0.f};

  for (int c0 = 0; c0 < 256; c0 += 64) {
    __syncthreads();
#pragma unroll
    for (int q = 0; q < 4; ++q) {
      int chunk = w * 4 + q; int row = chunk * 8 + lr;
      stage16(Abase + (size_t)row * 256 + c0 + srcj * 8, As + chunk * 512, l);
    }
#pragma unroll
    for (int q = 0; q < 2; ++q) {
      int chunk = w * 2 + q; int row = chunk * 8 + lr;
      stage16(Bbase + (size_t)row * 256 + c0 + srcj * 8, Bs + chunk * 512, l);
    }
    __syncthreads();
#pragma unroll
    for (int t = 0; t < 2; ++t) {
      s16x8 af[4], bf[4];
#pragma unroll
      for (int s = 0; s < 4; ++s) {
        int row = wo * 64 + s * 16 + lo;
        int phys = (t * 4 + hi) ^ (row & 7);
        af[s] = *reinterpret_cast<const s16x8*>(&As[row * 64 + phys * 8]);
      }
#pragma unroll
      for (int n = 0; n < 4; ++n) {
        int row = wn * 64 + n * 16 + lo;
        int phys = (t * 4 + hi) ^ (row & 7);
        bf[n] = *reinterpret_cast<const s16x8*>(&Bs[row * 64 + phys * 8]);
      }
#pragma unroll
      for (int s = 0; s < 4; ++s)
#pragma unroll
        for (int n = 0; n < 4; ++n)
          acc[s][n] = __builtin_amdgcn_mfma_f32_16x16x32_bf16(af[s], bf[n], acc[s][n], 0, 0, 0);
    }
  }

  // bias add
#pragma unroll
  for (int s = 0; s < 4; ++s)
#pragma unroll
    for (int i = 0; i < 4; ++i) {
      float bv = biasp[b * 768 + ot * 256 + wo * 64 + s * 16 + hi * 4 + i];
#pragma unroll
      for (int n = 0; n < 4; ++n) acc[s][n][i] += bv;
    }

  if (ot == 0) {
    // q: transpose -> bounce [64n][264] bf16, softmax per (n,head), fp8 store
    for (int r = 0; r < 2; ++r) {
      __syncthreads();
      if (wn == r) {
#pragma unroll
        for (int s = 0; s < 4; ++s)
#pragma unroll
          for (int n = 0; n < 4; ++n)
#pragma unroll
            for (int i = 0; i < 4; ++i) {
              int o_l = wo * 64 + s * 16 + hi * 4 + i;
              int n_l = n * 16 + lo;
              smem[n_l * 264 + o_l] = f2b(acc[s][n][i]);
            }
      }
      __syncthreads();
      {
        int n_l = tid >> 3, h = tid & 7;
        unsigned short* rowp = &smem[n_l * 264 + h * 32];
        float v[32];
        float m = -1e30f;
#pragma unroll
        for (int i = 0; i < 32; ++i) { v[i] = b2f(rowp[i]); m = fmaxf(m, v[i]); }
        float ssum = 0.f;
#pragma unroll
        for (int i = 0; i < 32; ++i) { v[i] = __expf(v[i] - m); ssum += v[i]; }
        float rr = 1.f / ssum;
#pragma unroll
        for (int i = 0; i < 32; ++i) rowp[i] = f2b(v[i] * rr);
      }
      __syncthreads();
#pragma unroll
      for (int it = 0; it < 2; ++it) {
        int task = tid + it * 512;                 // 1024 = 64n x 16 slots (16B fp8)
        int n_l = task >> 4, j = task & 15;
        const unsigned short* src = &smem[n_l * 264 + j * 16];
        u32x4 pk;
#pragma unroll
        for (int q2 = 0; q2 < 4; ++q2)
          pk[q2] = pk4f8(b2f(src[q2 * 4]), b2f(src[q2 * 4 + 1]),
                         b2f(src[q2 * 4 + 2]), b2f(src[q2 * 4 + 3]));
        *reinterpret_cast<u32x4*>(&qT8[((size_t)(b * NTOK + n0 + r * 64 + n_l)) * 256 + j * 16]) = pk;
      }
    }
  } else {
    // k/v -> fp8 bounce [128o][144], 16B stores with baked-in swizzle
    unsigned char* smem8 = reinterpret_cast<unsigned char*>(smem);
    int vbase = (ot == 1) ? 0 : 256;
    for (int r = 0; r < 2; ++r) {
      __syncthreads();
      if ((wo >> 1) == r) {
#pragma unroll
        for (int s = 0; s < 4; ++s)
#pragma unroll
          for (int n = 0; n < 4; ++n)
#pragma unroll
            for (int i = 0; i < 4; ++i) {
              int o_l = (wo & 1) * 64 + s * 16 + hi * 4 + i;
              int n_l = wn * 64 + n * 16 + lo;
              float val = acc[s][n][i];
              smem8[o_l * 144 + n_l] = (ot == 1) ? f2f8(__expf(val) * 0.0625f)
                                                 : f2f8(val);
            }
      }
      __syncthreads();
#pragma unroll
      for (int it = 0; it < 2; ++it) {
        int task = tid + it * 512;
        int o_l = task >> 3, j = task & 7;
        f32x4 v = *reinterpret_cast<const f32x4*>(&smem8[o_l * 144 + j * 16]);
        int row = vbase + r * 128 + o_l;
        int local16 = ((n0 & 511) >> 4) + j;
        int phys16 = local16 ^ (row & 7);
        *reinterpret_cast<f32x4*>(&kvb8[((size_t)(b * 512 + row)) * 32768
                                        + (n0 & ~511) + phys16 * 16]) = v;
      }
    }
  }
}

// ------------------------------------------------------------------
// K4: context via FP8 MFMA (E=exp(k)/16, V=v; scale cancels in ratio).
// ------------------------------------------------------------------
__global__ __launch_bounds__(256) void context_mfma(const unsigned char* __restrict__ kvb8,
                                                    float* __restrict__ ctx,
                                                    float* __restrict__ Ssum) {
  __shared__ unsigned char ctile[32768];
  unsigned char* kl = ctile;
  unsigned char* vl = ctile + 16384;
  int bh = blockIdx.y;
  int b = bh >> 3, h = bh & 7;
  int n0 = blockIdx.x * 512;
  int tid = threadIdx.x;
  int w = tid >> 6, l = tid & 63;
  int lo = l & 15, hi = l >> 4;
  const unsigned char* kb = kvb8 + ((size_t)(b * 512 + h * 32)) * 32768 + n0;
  const unsigned char* vb = kvb8 + ((size_t)(b * 512 + 256 + h * 32)) * 32768 + n0;

#pragma unroll
  for (int q = 0; q < 4; ++q) {
    int chunk = w * 4 + q;
    int row = chunk * 2 + (l >> 5);
    int blk = l & 31;
    stage16b(kb + (size_t)row * 32768 + blk * 16, kl + chunk * 1024, l);
    stage16b(vb + (size_t)row * 32768 + blk * 16, vl + chunk * 1024, l);
  }
  __syncthreads();

  f32x4 acc[2][2], accS[2];
#pragma unroll
  for (int fr = 0; fr < 2; ++fr) {
    accS[fr] = (f32x4){0.f, 0.f, 0.f, 0.f};
#pragma unroll
    for (int fc = 0; fc < 2; ++fc) acc[fr][fc] = (f32x4){0.f, 0.f, 0.f, 0.f};
  }
  long ones = 0x3838383838383838L;

#pragma unroll
  for (int ks = 0; ks < 4; ++ks) {
    int tb = w * 16 + ks * 4 + hi;
    long af[2], bf[2];
#pragma unroll
    for (int fr = 0; fr < 2; ++fr) {
      int row = fr * 16 + lo;
      int off = row * 512 + (((tb >> 1) ^ (row & 7)) << 4) + ((tb & 1) << 3);
      af[fr] = *reinterpret_cast<const long*>(&kl[off]);
      bf[fr] = *reinterpret_cast<const long*>(&vl[off]);
    }
#pragma unroll
    for (int fr = 0; fr < 2; ++fr) {
#pragma unroll
      for (int fc = 0; fc < 2; ++fc)
        acc[fr][fc] = __builtin_amdgcn_mfma_f32_16x16x32_fp8_fp8(af[fr], bf[fc], acc[fr][fc], 0, 0, 0);
      accS[fr] = __builtin_amdgcn_mfma_f32_16x16x32_fp8_fp8(af[fr], ones, accS[fr], 0, 0, 0);
    }
  }
  __syncthreads();

  float* lpart = reinterpret_cast<float*>(ctile);
  float* mine = lpart + w * 1056;
#pragma unroll
  for (int fr = 0; fr < 2; ++fr) {
#pragma unroll
    for (int fc = 0; fc < 2; ++fc)
#pragma unroll
      for (int i = 0; i < 4; ++i) {
        int row = fr * 16 + hi * 4 + i;
        int col = fc * 16 + lo;
        mine[row * 32 + col] = acc[fr][fc][i];
      }
    if (lo == 0)
#pragma unroll
      for (int i = 0; i < 4; ++i)
        mine[1024 + fr * 16 + hi * 4 + i] = accS[fr][i];
  }
  __syncthreads();
  float* cb = ctx + (size_t)bh * 1024;
  for (int i = tid; i < 1024; i += 256) {
    float v = lpart[i] + lpart[1056 + i] + lpart[2112 + i] + lpart[3168 + i];
    atomicAdd(&cb[i], v);
  }
  if (tid < 32) {
    int i = 1024 + tid;
    float v = lpart[i] + lpart[1056 + i] + lpart[2112 + i] + lpart[3168 + i];
    atomicAdd(&Ssum[b * 256 + h * 32 + tid], v);
  }
}

// ------------------------------------------------------------------
// K5: wctx8 = fp8( (1/Ssum) * wout @ ctx~ )
// ------------------------------------------------------------------
__global__ __launch_bounds__(256) void make_wctx(const float* __restrict__ wout,
                                                 const float* __restrict__ ctx,
                                                 const float* __restrict__ Ssum,
                                                 unsigned char* __restrict__ wctx8) {
  int o = blockIdx.x, b = blockIdx.y;
  int tid = threadIdx.x;
  int h = tid >> 5, d = tid & 31;
  const float* cb = ctx + ((size_t)(b * 8 + h)) * 1024 + d * 32;
  const float* wr = wout + (size_t)o * 256 + h * 32;
  float s = 0.f;
#pragma unroll
  for (int e = 0; e < 32; ++e) s += wr[e] * cb[e];
  s *= (1.f / Ssum[b * 256 + tid]);
  wctx8[((size_t)b * 256 + o) * 256 + tid] = f2f8(s);
}

// ------------------------------------------------------------------
// K6: out = wctx8 @ q8 + bias + x.  FP8xFP8 MFMA, BK=128 per outer step
// (2 outer steps, half the barriers), 48KB LDS, conflict-free 128B rows.
// f32x4 epilogue via bounce.
// ------------------------------------------------------------------
__global__ __launch_bounds__(512, 4) void out_gemm(const unsigned char* __restrict__ wctx8,
                                                   const unsigned char* __restrict__ qT8,
                                                   const float* __restrict__ bout,
                                                   const float* __restrict__ x,
                                                   float* __restrict__ out) {
  __shared__ unsigned char smem8[49152];   // As [0,32768) 256x128B, Bs [32768,49152) 128x128B
  unsigned char* As = smem8;
  unsigned char* Bs = smem8 + 32768;
  int bid = blockIdx.x;
  int L = (bid & 7) * 128 + (bid >> 3);    // 1024 = 8*128
  int b = L >> 8, nt = L & 255;
  int n0 = nt * 128;
  int tid = threadIdx.x;
  int w = tid >> 6, l = tid & 63;
  int hi = (l >> 4) & 3, lo = l & 15;
  int wo = w >> 1, wn = w & 1;
  int lr = l >> 3, lj = l & 7;             // staging: 8 rows/chunk, 8 lanes x 16B per row
  int srcj = lj ^ lr;
  const unsigned char* Abase = wctx8 + (size_t)b * 65536;
  const unsigned char* Bbase = qT8 + ((size_t)(b * NTOK + n0)) * 256;

  f32x4 acc[4][4];
#pragma unroll
  for (int s = 0; s < 4; ++s)
#pragma unroll
    for (int n = 0; n < 4; ++n) acc[s][n] = (f32x4){0.f, 0.f, 0.f, 0.f};

  for (int c0 = 0; c0 < 256; c0 += 128) {
    __syncthreads();
#pragma unroll
    for (int q = 0; q < 4; ++q) {          // A: 32 chunks of 1KB (8 rows x 128B)
      int chunk = w * 4 + q; int row = chunk * 8 + lr;
      stage16b(Abase + (size_t)row * 256 + c0 + srcj * 16, As + chunk * 1024, l);
    }
#pragma unroll
    for (int q = 0; q < 2; ++q) {          // B: 16 chunks
      int chunk = w * 2 + q; int row = chunk * 8 + lr;
      stage16b(Bbase + (size_t)row * 256 + c0 + srcj * 16, Bs + chunk * 1024, l);
    }
    __syncthreads();
#pragma unroll
    for (int t = 0; t < 4; ++t) {          // K=32 per t
      int blk16 = t * 2 + (hi >> 1);
      int sub8  = (hi & 1) * 8;
      long af[4], bf[4];
#pragma unroll
      for (int s = 0; s < 4; ++s) {
        int row = wo * 64 + s * 16 + lo;
        af[s] = *reinterpret_cast<const long*>(&As[row * 128 + ((blk16 ^ (row & 7)) << 4) + sub8]);
      }
#pragma unroll
      for (int n = 0; n < 4; ++n) {
        int row = wn * 64 + n * 16 + lo;
        bf[n] = *reinterpret_cast<const long*>(&Bs[row * 128 + ((blk16 ^ (row & 7)) << 4) + sub8]);
      }
#pragma unroll
      for (int s = 0; s < 4; ++s)
#pragma unroll
        for (int n = 0; n < 4; ++n)
          acc[s][n] = __builtin_amdgcn_mfma_f32_16x16x32_fp8_fp8(af[s], bf[n], acc[s][n], 0, 0, 0);
    }
  }

  // epilogue: f32 bounce [64][132], coalesced f32x4 RMW out = acc + bias + x
  float* bounce = reinterpret_cast<float*>(smem8);
  const float* xb = x + (size_t)b * 256 * NTOK;
  for (int r = 0; r < 4; ++r) {
    __syncthreads();
    if (wo == r) {
#pragma unroll
      for (int s = 0; s < 4; ++s)
#pragma unroll
        for (int n = 0; n < 4; ++n)
#pragma unroll
          for (int i = 0; i < 4; ++i) {
            int o_l = s * 16 + hi * 4 + i;
            int n_l = wn * 64 + n * 16 + lo;
            bounce[o_l * 132 + n_l] = acc[s][n][i];
          }
    }
    __syncthreads();
#pragma unroll
    for (int it = 0; it < 4; ++it) {
      int task = tid + it * 512;
      int o_l = task >> 5, q4 = task & 31;
      int o = r * 64 + o_l;
      f32x4 a = *reinterpret_cast<const f32x4*>(&bounce[o_l * 132 + q4 * 4]);
      f32x4 xv = *reinterpret_cast<const f32x4*>(&xb[(size_t)o * NTOK + n0 + q4 * 4]);
      float bo = bout[o];
      f32x4 rlt = { a.x + bo + xv.x, a.y + bo + xv.y, a.z + bo + xv.z, a.w + bo + xv.w };
      *reinterpret_cast<f32x4*>(&out[((size_t)b * 256 + o) * NTOK + n0 + q4 * 4]) = rlt;
    }
  }
}

// ------------------------------------------------------------------
extern "C" void kernel_launch(void* const* d_in, const int* in_sizes, int n_in,
                              void* d_out, int out_size, void* d_ws, size_t ws_size,
                              hipStream_t stream) {
  const float* x     = (const float*)d_in[0];
  const float* gamma = (const float*)d_in[1];
  const float* beta  = (const float*)d_in[2];
  const float* wqkv  = (const float*)d_in[3];
  const float* wout  = (const float*)d_in[4];
  const float* bout  = (const float*)d_in[5];
  float* out = (float*)d_out;

  if (ws_size < WS_NEEDED) return;

  char* ws = (char*)d_ws;
  float* gstat        = (float*)(ws + OFF_GSTAT);
  float* Ssum         = (float*)(ws + OFF_SSUM);
  float* ctx          = (float*)(ws + OFF_CTX);
  unsigned char* wctx8 = (unsigned char*)(ws + OFF_WCTX8);
  float* biasp        = (float*)(ws + OFF_BIASP);
  unsigned short* Wp  = (unsigned short*)(ws + OFF_WP);
  unsigned short* xT  = (unsigned short*)(ws + OFF_XT);
  unsigned char* qT8  = (unsigned char*)(ws + OFF_QT);
  unsigned char* kvb8 = (unsigned char*)(ws + OFF_KVB);

  // zero: gstat, Ssum, ctx
  hipMemsetAsync(ws, 0, OFF_CTX + 131072u, stream);

  gn_fused  <<<dim3(512, 4), 256, 0, stream>>>(x, gstat, xT);
  fold_w    <<<dim3(768, 4), 256, 0, stream>>>(wqkv, gamma, beta, gstat, Wp, biasp);
  qkv_gemm  <<<3072, 512, 0, stream>>>(Wp, biasp, xT, qT8, kvb8);
  context_mfma<<<dim3(64, 32), 256, 0, stream>>>(kvb8, ctx, Ssum);
  make_wctx <<<dim3(256, 4), 256, 0, stream>>>(wout, ctx, Ssum, wctx8);
  out_gemm  <<<1024, 512, 0, stream>>>(wctx8, qT8, bout, x, out);
}